// Round 1
// baseline (348.324 us; speedup 1.0000x reference)
//
#include <hip/hip_runtime.h>

#define IMG 28
#define NPIX (IMG * IMG)          // 784
#define NVEC (NPIX / 4)           // 196 float4 per image
#define CENTER 14

// out = x everywhere except the annulus {(t-1)^2 < d2 <= t^2} (t=0: center
// pixel only), where out = x + conv3x3(x) + b.  Cross-correlation, SAME pad.
__global__ __launch_bounds__(256) void SuperResolution_89876485636254_kernel(
    const float* __restrict__ x,
    const int*   __restrict__ t,
    const float* __restrict__ Wk,
    const float* __restrict__ bias,
    float*       __restrict__ out)
{
    __shared__ float s[4][NPIX];

    const int wave = threadIdx.x >> 6;
    const int lane = threadIdx.x & 63;
    const int img  = blockIdx.x * 4 + wave;

    const float4* __restrict__ xin4 = (const float4*)(x + (size_t)img * NPIX);
    float4*       __restrict__ out4 = (float4*)(out + (size_t)img * NPIX);
    float4*       s4 = (float4*)s[wave];

    // ---- stage image into LDS (and keep values in registers for copy path)
    float4 vals[4];
    #pragma unroll
    for (int kk = 0; kk < 4; ++kk) {
        int k = lane + kk * 64;
        if (k < NVEC) {
            vals[kk] = xin4[k];
            s4[k]    = vals[kk];
        }
    }

    // uniform per-wave metadata
    const int rt  = t[img];
    const int r2  = rt * rt;
    const int r12 = (rt - 1) * (rt - 1);  // only consulted when rt >= 1
    float w[9];
    #pragma unroll
    for (int i = 0; i < 9; ++i) w[i] = Wk[i];
    const float bb = bias[0];

    __syncthreads();

    const float* __restrict__ simg = s[wave];

    #pragma unroll
    for (int kk = 0; kk < 4; ++kk) {
        int k = lane + kk * 64;
        if (k < NVEC) {
            float4 v = vals[kk];
            float r[4] = {v.x, v.y, v.z, v.w};
            const int p = 4 * k;
            const int i = p / IMG;        // all 4 pixels share the row (28 % 4 == 0)
            const int j0 = p - i * IMG;
            const int di = i - CENTER;
            const int di2 = di * di;
            #pragma unroll
            for (int e = 0; e < 4; ++e) {
                const int j  = j0 + e;
                const int dj = j - CENTER;
                const int d2 = di2 + dj * dj;
                const bool in_t  = (d2 <= r2);
                const bool in_t1 = (rt >= 1) && (d2 <= r12);
                if (in_t && !in_t1) {
                    float acc = bb;
                    #pragma unroll
                    for (int a = 0; a < 3; ++a) {
                        const int ii = i + a - 1;
                        if (ii >= 0 && ii < IMG) {
                            #pragma unroll
                            for (int c = 0; c < 3; ++c) {
                                const int jj = j + c - 1;
                                if (jj >= 0 && jj < IMG)
                                    acc += w[a * 3 + c] * simg[ii * IMG + jj];
                            }
                        }
                    }
                    r[e] += acc;
                }
            }
            float4 ov;
            ov.x = r[0]; ov.y = r[1]; ov.z = r[2]; ov.w = r[3];
            out4[k] = ov;
        }
    }
}

extern "C" void kernel_launch(void* const* d_in, const int* in_sizes, int n_in,
                              void* d_out, int out_size, void* d_ws, size_t ws_size,
                              hipStream_t stream) {
    const float* x    = (const float*)d_in[0];
    const int*   t    = (const int*)d_in[1];
    const float* Wk   = (const float*)d_in[2];
    const float* bias = (const float*)d_in[3];
    float*       out  = (float*)d_out;

    const int B = in_sizes[0] / NPIX;        // 65536
    const int blocks = B / 4;                // 4 images per 256-thread block

    SuperResolution_89876485636254_kernel<<<blocks, 256, 0, stream>>>(
        x, t, Wk, bias, out);
}